// Round 8
// baseline (249.157 us; speedup 1.0000x reference)
//
#include <hip/hip_runtime.h>
#include <hip/hip_cooperative_groups.h>

namespace cg = cooperative_groups;

// BackprojectDepth: out[b, 0:3, k] = depth[b, idx] * (inv_K[b,:3,:3] @ [gx, gy, 1])
//                   out[b, 3, k]   = 1.0
// idx = top_k_indices[b,k], gx = idx % W, gy = idx / W.
// pix_coords input is a meshgrid -> recomputed arithmetically, never read.
//
// Round 8: single cooperative kernel, two phases.
//  Phase A: coalesced sequential read of depth (each XCD reads only its 2
//           batches, 3.75MB < 4MB L2; also fills L3) + write constant w=1
//           channel. Sequential HBM fetch at full efficiency instead of
//           random 64B demand misses.
//  grid.sync()  (all 2048 blocks co-resident: 8 blocks/CU x 256 CUs)
//  Phase B: R3 gather structure (ILP=4, nt idx load, nt out stores). Gathers
//           hit warm L2; stream-evicted lines re-hit warm L3 instead of HBM.
// R6 lesson: sc0 kills L2 caching -> plain gathers. R7 lesson: separate warm
// kernel doesn't stick (launch gap + stream eviction) -> fuse + sync.

#define BB 16
#define HH 384
#define WW 1280
#define HWSZ (HH * WW)           // 491520
#define HW4 (HWSZ / 4)           // 122880 float4 per batch
#define KK 131072
#define NXCD 8
#define BLOCKS_PER_BATCH (KK / (256 * 4))    // 128
#define TOTAL_BLOCKS (BB * BLOCKS_PER_BATCH) // 2048
#define WARM_F4_PER_BLOCK (HW4 / BLOCKS_PER_BATCH) // 960 (= 256*3.75)

typedef float v4f __attribute__((ext_vector_type(4)));
typedef int   v4i __attribute__((ext_vector_type(4)));

__device__ __forceinline__ void xcd_map(int bid, int& b, int& blk) {
    const int xcd  = bid & (NXCD - 1);
    const int slot = bid >> 3;                              // 0..255
    const int logical = xcd * (TOTAL_BLOCKS / NXCD) + slot; // 0..2047
    b   = logical >> 7;   // batch (2 per XCD)
    blk = logical & 127;  // block within batch
}

__global__ __launch_bounds__(256) void backproject_fused(
    const float* __restrict__ depth,   // B*HW
    const float* __restrict__ invK,    // B*16
    const int*   __restrict__ topk,    // B*K
    float*       __restrict__ out)     // B*4*K
{
    int b, blk;
    xcd_map(blockIdx.x, b, blk);
    const int k0 = blk * 1024 + threadIdx.x * 4;

    // ---------------- Phase A: sequential L2/L3 warm + w channel ----------
    {
        const v4f* __restrict__ d4 = reinterpret_cast<const v4f*>(depth) + b * HW4;
        float acc = 0.f;
#pragma unroll
        for (int it = 0; it < 4; ++it) {
            const int i = blk * WARM_F4_PER_BLOCK + it * 256 + threadIdx.x;
            if (it < 3 || i < (blk + 1) * WARM_F4_PER_BLOCK) {
                const v4f v = d4[i];                 // plain load: allocates L2+L3
                acc += v[0] + v[1] + v[2] + v[3];
            }
        }
        asm volatile("" :: "v"(acc));                // keep loads live

        float* __restrict__ obw = out + (size_t)b * 4 * KK + 3 * KK + k0;
        v4f vw = {1.f, 1.f, 1.f, 1.f};
        __builtin_nontemporal_store(vw, reinterpret_cast<v4f*>(obw));
    }

    cg::this_grid().sync();

    // ---------------- Phase B: gather + project (R3 structure) ------------
    const float* __restrict__ M = invK + b * 16;
    const float m00 = M[0], m01 = M[1], m02 = M[2];
    const float m10 = M[4], m11 = M[5], m12 = M[6];
    const float m20 = M[8], m21 = M[9], m22 = M[10];

    const v4i idx4 = __builtin_nontemporal_load(
        reinterpret_cast<const v4i*>(topk + b * KK + k0));
    const float* __restrict__ db = depth + b * HWSZ;

    const int idxs[4] = {idx4[0], idx4[1], idx4[2], idx4[3]};
    float d[4];
#pragma unroll
    for (int j = 0; j < 4; ++j) d[j] = db[idxs[j]];  // plain loads: L1+L2 cached

    float ox[4], oy[4], oz[4];
#pragma unroll
    for (int j = 0; j < 4; ++j) {
        const int idx = idxs[j];
        const float gx = (float)(idx % WW);
        const float gy = (float)(idx / WW);
        ox[j] = d[j] * fmaf(m00, gx, fmaf(m01, gy, m02));
        oy[j] = d[j] * fmaf(m10, gx, fmaf(m11, gy, m12));
        oz[j] = d[j] * fmaf(m20, gx, fmaf(m21, gy, m22));
    }

    float* __restrict__ ob = out + (size_t)b * 4 * KK + k0;
    v4f vx = {ox[0], ox[1], ox[2], ox[3]};
    v4f vy = {oy[0], oy[1], oy[2], oy[3]};
    v4f vz = {oz[0], oz[1], oz[2], oz[3]};
    __builtin_nontemporal_store(vx, reinterpret_cast<v4f*>(ob + 0 * KK));
    __builtin_nontemporal_store(vy, reinterpret_cast<v4f*>(ob + 1 * KK));
    __builtin_nontemporal_store(vz, reinterpret_cast<v4f*>(ob + 2 * KK));
}

extern "C" void kernel_launch(void* const* d_in, const int* in_sizes, int n_in,
                              void* d_out, int out_size, void* d_ws, size_t ws_size,
                              hipStream_t stream) {
    const float* depth = (const float*)d_in[0];     // (B,1,H,W) f32
    const float* invK  = (const float*)d_in[1];     // (B,4,4) f32
    // d_in[2] = pix_coords — intentionally unused (recomputed from index)
    const int*   topk  = (const int*)d_in[3];       // (B,K) i32
    float* out = (float*)d_out;                     // (B,4,K) f32

    void* args[] = {(void*)&depth, (void*)&invK, (void*)&topk, (void*)&out};
    hipLaunchCooperativeKernel((const void*)backproject_fused,
                               dim3(TOTAL_BLOCKS), dim3(256),
                               args, 0, stream);
}

// Round 9
// 24.859 us; speedup vs baseline: 10.0230x; 10.0230x over previous
//
#include <hip/hip_runtime.h>

// BackprojectDepth: out[b, 0:3, k] = depth[b, idx] * (inv_K[b,:3,:3] @ [gx, gy, 1])
//                   out[b, 3, k]   = 1.0
// idx = top_k_indices[b,k], gx = idx % W, gy = idx / W.
// pix_coords input is a meshgrid -> recomputed arithmetically, never read.
//
// Round 9: R3 best structure (2048 blocks, ILP=4, XCD remap, nt idx load,
// nt out stores) + fused per-block L2/L3 warm, NO grid sync (R8: grid.sync
// costs ~230us). Each block: issue idx load -> issue coalesced plain loads of
// its 15KB depth slice (cooperatively covers the batch's 1.9MB; fills this
// XCD's L2 + die L3 sequentially) -> gathers. Same dispatch = no boundary
// flush; warm->use gap is one phase; nt streams shouldn't evict depth.
// R6 lesson: no sc0 on gathers. R8 lesson: L3 partially survives poison fills.

#define BB 16
#define HH 384
#define WW 1280
#define HWSZ (HH * WW)           // 491520
#define HW4 (HWSZ / 4)           // 122880 float4 per batch
#define KK 131072
#define NXCD 8
#define BLOCKS_PER_BATCH (KK / (256 * 4))    // 128
#define TOTAL_BLOCKS (BB * BLOCKS_PER_BATCH) // 2048
#define WARM_F4_PER_BLOCK (HW4 / BLOCKS_PER_BATCH) // 960 (15KB/block)

typedef float v4f __attribute__((ext_vector_type(4)));
typedef int   v4i __attribute__((ext_vector_type(4)));

__device__ __forceinline__ void xcd_map(int bid, int& b, int& blk) {
    const int xcd  = bid & (NXCD - 1);
    const int slot = bid >> 3;                              // 0..255
    const int logical = xcd * (TOTAL_BLOCKS / NXCD) + slot; // 0..2047
    b   = logical >> 7;   // batch (2 per XCD, 3.75MB < 4MB L2)
    blk = logical & 127;  // block within batch
}

__global__ __launch_bounds__(256) void backproject_kernel(
    const float* __restrict__ depth,   // B*HW
    const float* __restrict__ invK,    // B*16
    const int*   __restrict__ topk,    // B*K
    float*       __restrict__ out)     // B*4*K
{
    int b, blk;
    xcd_map(blockIdx.x, b, blk);
    const int k0 = blk * 1024 + threadIdx.x * 4;

    // Issue idx load first (nt, read-once stream).
    const v4i idx4 = __builtin_nontemporal_load(
        reinterpret_cast<const v4i*>(topk + b * KK + k0));

    // Warm: coalesced plain loads of this block's 15KB depth slice
    // (allocates L2+L3 sequentially while idx is in flight).
    const v4f* __restrict__ w4 =
        reinterpret_cast<const v4f*>(depth) + b * HW4 + blk * WARM_F4_PER_BLOCK;
    const int t = threadIdx.x;
    const v4f w0 = w4[t];
    const v4f w1 = w4[256 + t];
    const v4f w2 = w4[512 + t];
    const v4f w3 = w4[768 + (t < 192 ? t : 0)];   // 960 f4/block tail, branchless

    const float* __restrict__ M = invK + b * 16;
    const float m00 = M[0], m01 = M[1], m02 = M[2];
    const float m10 = M[4], m11 = M[5], m12 = M[6];
    const float m20 = M[8], m21 = M[9], m22 = M[10];

    const float* __restrict__ db = depth + b * HWSZ;
    const int idxs[4] = {idx4[0], idx4[1], idx4[2], idx4[3]};
    float d[4];
#pragma unroll
    for (int j = 0; j < 4; ++j) d[j] = db[idxs[j]];  // plain gathers: L1+L2+L3

    // Keep warm loads alive without forcing an early waitcnt.
    asm volatile("" :: "v"(w0), "v"(w1), "v"(w2), "v"(w3));

    float ox[4], oy[4], oz[4];
#pragma unroll
    for (int j = 0; j < 4; ++j) {
        const int idx = idxs[j];
        const float gx = (float)(idx % WW);
        const float gy = (float)(idx / WW);
        ox[j] = d[j] * fmaf(m00, gx, fmaf(m01, gy, m02));
        oy[j] = d[j] * fmaf(m10, gx, fmaf(m11, gy, m12));
        oz[j] = d[j] * fmaf(m20, gx, fmaf(m21, gy, m22));
    }

    float* __restrict__ ob = out + (size_t)b * 4 * KK + k0;
    v4f vx = {ox[0], ox[1], ox[2], ox[3]};
    v4f vy = {oy[0], oy[1], oy[2], oy[3]};
    v4f vz = {oz[0], oz[1], oz[2], oz[3]};
    v4f vw = {1.f, 1.f, 1.f, 1.f};
    __builtin_nontemporal_store(vx, reinterpret_cast<v4f*>(ob + 0 * KK));
    __builtin_nontemporal_store(vy, reinterpret_cast<v4f*>(ob + 1 * KK));
    __builtin_nontemporal_store(vz, reinterpret_cast<v4f*>(ob + 2 * KK));
    __builtin_nontemporal_store(vw, reinterpret_cast<v4f*>(ob + 3 * KK));
}

extern "C" void kernel_launch(void* const* d_in, const int* in_sizes, int n_in,
                              void* d_out, int out_size, void* d_ws, size_t ws_size,
                              hipStream_t stream) {
    const float* depth = (const float*)d_in[0];     // (B,1,H,W) f32
    const float* invK  = (const float*)d_in[1];     // (B,4,4) f32
    // d_in[2] = pix_coords — intentionally unused (recomputed from index)
    const int*   topk  = (const int*)d_in[3];       // (B,K) i32
    float* out = (float*)d_out;                     // (B,4,K) f32

    backproject_kernel<<<TOTAL_BLOCKS, 256, 0, stream>>>(depth, invK, topk, out);
}